// Round 9
// baseline (360.532 us; speedup 1.0000x reference)
//
#include <hip/hip_runtime.h>

// incepLayer, float32 in/out. out = concat([h, f1, f2, f3]); f_k are alpha-
// mixes of P^k h, P = weighted segment_sum over edges, e = d[src]*d[dst].
//
// R9 = R8 structure + padded-CSR edge lists (replaces CAP=64 buckets).
// Evidence (R8 counters): agg3 FETCH 37.6 MB ~= 4 x bucket 10.24 MB — the
// ONLY significant HBM cost of chunking is bucket re-read per chunk; table
// contributes ~0 FETCH. CSR cuts per-chunk bucket bytes 10.24 -> ~3 MB.
//  - csr[]: one u32/edge = f16(w)<<16 | src(16b), grouped by dst, each
//    node's range padded to x4 with ZEROED slots (w=0, s=0) -> uniform
//    4-unrolled inner loop, no tail masking, no poison hazard.
//  - offs[] via single-block LDS scan of padded counts.
//  - tab[c][node][16 u32]: chunk c = 32 dims = 2.56 MB; blockIdx%8 in
//    {2c,2c+1} pins chunk c to one XCD pair end-to-end (R8 mapping).
//  - NT only on pure streams (dst/src reads, h reads, final out stores).
// Numerics: f16 weights, bf16 rows, f32 acc (verified class, absmax 0.0625);
// CSR only reorders f32 summation (~1e-6, invisible vs bf16 quantization).

#define NN  40000
#define NE  640000
#define NCH 4    // dim chunks (32 dims each)
#define CWU 16   // u32 words per chunk-row (2 dims per u32)

typedef unsigned int uint;
typedef unsigned short ushort;
typedef float f32x2 __attribute__((ext_vector_type(2)));

__device__ inline ushort f2h(float f) {
    _Float16 h = (_Float16)f;
    return *(ushort*)&h;
}
__device__ inline float h2f(ushort u) {
    _Float16 h = *(_Float16*)&u;
    return (float)h;
}
__device__ inline ushort f2bf(float f) {  // round-to-nearest-even
    uint x = __float_as_uint(f);
    x += 0x7fffu + ((x >> 16) & 1u);
    return (ushort)(x >> 16);
}
__device__ inline uint pack_bf2(float x, float y) {
    return ((uint)f2bf(y) << 16) | (uint)f2bf(x);
}
__device__ inline float bflo(uint u) { return __uint_as_float(u << 16); }
__device__ inline float bfhi(uint u) { return __uint_as_float(u & 0xffff0000u); }

// ---- degree count ----------------------------------------------------------
__global__ __launch_bounds__(256) void count_k(
    const int* __restrict__ dst, int* __restrict__ counts) {
    int e = blockIdx.x * 256 + threadIdx.x;   // NE % 256 == 0
    int v = __builtin_nontemporal_load(dst + e);
    atomicAdd(&counts[v], 1);
}

// ---- exclusive scan of x4-padded counts; offs[NN] = total; cursor = offs ---
__global__ __launch_bounds__(1024) void scan_k(
    const int* __restrict__ counts, int* __restrict__ offs,
    int* __restrict__ cursor) {
    __shared__ int part[1024];
    int tid = threadIdx.x;
    int base = tid * 40;                       // 1024*40 = 40960 >= NN
    int s = 0;
    for (int i = 0; i < 40; ++i) {
        int idx = base + i;
        if (idx < NN) s += (counts[idx] + 3) & ~3;
    }
    part[tid] = s;
    __syncthreads();
    for (int d = 1; d < 1024; d <<= 1) {       // Hillis-Steele inclusive
        int v = part[tid];
        int a = (tid >= d) ? part[tid - d] : 0;
        __syncthreads();
        part[tid] = v + a;
        __syncthreads();
    }
    int run = (tid > 0) ? part[tid - 1] : 0;   // exclusive prefix
    for (int i = 0; i < 40; ++i) {
        int idx = base + i;
        if (idx < NN) {
            offs[idx] = run;
            cursor[idx] = run;
            run += (counts[idx] + 3) & ~3;
        }
    }
    if (tid == 1023) offs[NN] = part[1023];
}

// ---- fill CSR: slot via per-node cursor; pad slots stay 0 (memset) ---------
__global__ __launch_bounds__(256) void fill_k(
    const int* __restrict__ src, const int* __restrict__ dst,
    const float* __restrict__ deg,
    int* __restrict__ cursor, uint* __restrict__ csr) {
    int e = blockIdx.x * 256 + threadIdx.x;
    int s = __builtin_nontemporal_load(src + e);
    int v = __builtin_nontemporal_load(dst + e);
    float w = deg[s] * deg[v];
    int slot = atomicAdd(&cursor[v], 1);
    csr[slot] = ((uint)f2h(w) << 16) | (uint)s;
}

// ---- convert h (f32) -> chunk-major bf16 tables, chunk->XCD-pair affine ----
__global__ __launch_bounds__(256) void cvt_k(
    const float* __restrict__ h, uint* __restrict__ tab) {
    int b   = blockIdx.x;
    int c   = (b & 7) >> 1;
    int wi  = (b >> 3) * 2 + (b & 1);
    int tgl = wi * 256 + threadIdx.x;         // u32 index within chunk
    int v = tgl >> 4, t = tgl & 15;
    f32x2 f = __builtin_nontemporal_load(
        (const f32x2*)(h + (size_t)v * 128 + c * 32 + t * 2));
    tab[(size_t)c * NN * CWU + tgl] = pack_bf2(f.x, f.y);  // seeds L2
}

// ---- core gather: subgroup (16 lanes) per node; lane t owns dims 2t,2t+1 ---
__device__ inline void gather_c(
    const uint* __restrict__ tabc, const int* __restrict__ offs,
    const uint* __restrict__ csr, int v, int t, float* a0, float* a1) {
    int o0 = offs[v], o1 = offs[v + 1];       // padded range, multiple of 4
    float x0 = 0.f, x1 = 0.f;
    for (int j = o0; j < o1; j += 4) {
        uint u0 = csr[j + 0];                 // broadcast within subgroup
        uint u1 = csr[j + 1];
        uint u2 = csr[j + 2];
        uint u3 = csr[j + 3];
        uint f0 = tabc[(size_t)(u0 & 0xffffu) * CWU + t];   // L2-chunk
        uint f1 = tabc[(size_t)(u1 & 0xffffu) * CWU + t];
        uint f2 = tabc[(size_t)(u2 & 0xffffu) * CWU + t];
        uint f3 = tabc[(size_t)(u3 & 0xffffu) * CWU + t];
        float w0 = h2f((ushort)(u0 >> 16));   // pad slots: u=0 -> w=0
        float w1 = h2f((ushort)(u1 >> 16));
        float w2 = h2f((ushort)(u2 >> 16));
        float w3 = h2f((ushort)(u3 >> 16));
        x0 = fmaf(w0, bflo(f0), x0); x1 = fmaf(w0, bfhi(f0), x1);
        x0 = fmaf(w1, bflo(f1), x0); x1 = fmaf(w1, bfhi(f1), x1);
        x0 = fmaf(w2, bflo(f2), x0); x1 = fmaf(w2, bfhi(f2), x1);
        x0 = fmaf(w3, bflo(f3), x0); x1 = fmaf(w3, bfhi(f3), x1);
    }
    *a0 = x0; *a1 = x1;
}

// ---- aggregation pass: chunk-affine gather -> chunk-major bf16 table -------
__global__ __launch_bounds__(256) void agg_k(
    const uint* __restrict__ tin, const int* __restrict__ offs,
    const uint* __restrict__ csr, uint* __restrict__ tout) {
    int b  = blockIdx.x;
    int c  = (b & 7) >> 1;
    int wi = (b >> 3) * 2 + (b & 1);          // [0,2500), 16 nodes per block
    int lane = threadIdx.x & 63, wave = threadIdx.x >> 6;
    int n = lane >> 4, t = lane & 15;
    int v = wi * 16 + wave * 4 + n;
    float a0, a1;
    gather_c(tin + (size_t)c * NN * CWU, offs, csr, v, t, &a0, &a1);
    tout[(size_t)c * NN * CWU + (size_t)v * CWU + t] = pack_bf2(a0, a1);
}

// ---- final pass: gather P^3 chunk + alpha-combine + write 4 sections -------
__global__ __launch_bounds__(256) void agg3_k(
    const uint* __restrict__ p2t, const uint* __restrict__ p1t,
    const float* __restrict__ h, const int* __restrict__ offs,
    const uint* __restrict__ csr, const float* __restrict__ alphas,
    float* __restrict__ out) {
    int b  = blockIdx.x;
    int c  = (b & 7) >> 1;
    int wi = (b >> 3) * 2 + (b & 1);
    int lane = threadIdx.x & 63, wave = threadIdx.x >> 6;
    int n = lane >> 4, t = lane & 15;
    int v = wi * 16 + wave * 4 + n;
    float p30, p31;
    gather_c(p2t + (size_t)c * NN * CWU, offs, csr, v, t, &p30, &p31);

    float a0 = alphas[0], a1 = alphas[1], a2 = alphas[2];
    float a3 = alphas[3], a4 = alphas[4], a5 = alphas[5];
    float c1p = a0, c1h = 1.f - a0;
    float c2pp = a2 * a1;
    float c2p  = a2 * (1.f - a1) + (1.f - a2) * a1;
    float c2h  = (1.f - a2) * (1.f - a1);
    float s2pp = a4 * a3;
    float s2p  = a4 * (1.f - a3) + (1.f - a4) * a3;
    float s2h  = (1.f - a4) * (1.f - a3);
    float c3ppp = a5 * s2pp;
    float c3pp  = a5 * s2p + (1.f - a5) * s2pp;
    float c3p   = a5 * s2h + (1.f - a5) * s2p;
    float c3h   = (1.f - a5) * s2h;

    size_t idx = (size_t)c * NN * CWU + (size_t)v * CWU + t;
    uint u1 = p1t[idx], u2 = p2t[idx];
    float q10 = bflo(u1), q11 = bfhi(u1);
    float q20 = bflo(u2), q21 = bfhi(u2);
    f32x2 hf = __builtin_nontemporal_load(
        (const f32x2*)(h + (size_t)v * 128 + c * 32 + t * 2));

    f32x2 r1, r2, r3;
    r1.x = c1p * q10 + c1h * hf.x;
    r1.y = c1p * q11 + c1h * hf.y;
    r2.x = c2pp * q20 + c2p * q10 + c2h * hf.x;
    r2.y = c2pp * q21 + c2p * q11 + c2h * hf.y;
    r3.x = c3ppp * p30 + c3pp * q20 + c3p * q10 + c3h * hf.x;
    r3.y = c3ppp * p31 + c3pp * q21 + c3p * q11 + c3h * hf.y;

    float* o = out + (size_t)v * 512 + c * 32 + t * 2;  // 128 B per (v,sec)
    __builtin_nontemporal_store(hf, (f32x2*)(o));
    __builtin_nontemporal_store(r1, (f32x2*)(o + 128));
    __builtin_nontemporal_store(r2, (f32x2*)(o + 256));
    __builtin_nontemporal_store(r3, (f32x2*)(o + 384));
}

extern "C" void kernel_launch(void* const* d_in, const int* in_sizes, int n_in,
                              void* d_out, int out_size, void* d_ws, size_t ws_size,
                              hipStream_t stream) {
    const float* h      = (const float*)d_in[0];
    const float* deg    = (const float*)d_in[1];
    const float* alphas = (const float*)d_in[2];
    const int*   src    = (const int*)d_in[3];
    const int*   dst    = (const int*)d_in[4];
    float* out = (float*)d_out;

    // ws layout (bytes):
    // counts @0 (160,000) | offs @160,000 (160,016) | cursor @320,016
    // (160,000) | csr @480,064 (3,200,000) | hb @3,680,256 | p1b @13,920,256
    // | p2b @24,160,256 | end 34,400,256  (< prior 41.1 MB request)
    char* ws = (char*)d_ws;
    int*  counts = (int*)(ws + 0);
    int*  offs   = (int*)(ws + 160000);
    int*  cursor = (int*)(ws + 320016);
    uint* csr    = (uint*)(ws + 480064);
    uint* hb     = (uint*)(ws + 3680256);
    uint* p1b    = (uint*)(ws + 13920256);
    uint* p2b    = (uint*)(ws + 24160256);

    hipMemsetAsync(counts, 0, NN * sizeof(int), stream);
    hipMemsetAsync(csr, 0, 3200000, stream);   // pad slots -> w=0, s=0
    count_k<<<NE / 256, 256, 0, stream>>>(dst, counts);
    scan_k<<<1, 1024, 0, stream>>>(counts, offs, cursor);
    fill_k<<<NE / 256, 256, 0, stream>>>(src, dst, deg, cursor, csr);
    cvt_k<<<NN * NCH * CWU / 256, 256, 0, stream>>>(h, hb);        // 10000

    agg_k<<<NN * NCH / 16, 256, 0, stream>>>(hb,  offs, csr, p1b); // 10000
    agg_k<<<NN * NCH / 16, 256, 0, stream>>>(p1b, offs, csr, p2b); // 10000
    agg3_k<<<NN * NCH / 16, 256, 0, stream>>>(p2b, p1b, h, offs, csr,
                                              alphas, out);        // 10000
}